// Round 4
// baseline (376.448 us; speedup 1.0000x reference)
//
#include <hip/hip_runtime.h>
#include <hip/hip_bf16.h>
#include <math.h>

#define B_ 8
#define C_ 128
#define P_ 100000
#define K_ 14
#define H_ 8
#define DH_ 16
#define C2_ (2*C_)
#define E3_ (3*C_)
#define R2 0.25f

typedef float f32x4_t __attribute__((ext_vector_type(4)));

// -------------------- kernel 1: geometry -> fp32 mask planes + nearest + counts --------------------
__global__ void geom_kernel(const float* __restrict__ pts,
                            const float* __restrict__ cav,
                            float* __restrict__ maskf,
                            unsigned char* __restrict__ nearest,
                            int* __restrict__ counts) {
    __shared__ float cx[K_], cy[K_], cz[K_];
    __shared__ int sm[K_];
    int tid = threadIdx.x;
    if (tid < K_) {
        cx[tid] = cav[tid*3+0];
        cy[tid] = cav[tid*3+1];
        cz[tid] = cav[tid*3+2];
        sm[tid] = 0;
    }
    __syncthreads();
    int p = blockIdx.x * blockDim.x + tid;
    bool valid = (p < P_);
    int pc = valid ? p : (P_ - 1);
    float px = pts[pc*3+0], py = pts[pc*3+1], pz = pts[pc*3+2];
    unsigned m = 0;
    float best = 1e30f;
    int bi = 0;
    float mv[K_];
    #pragma unroll
    for (int k = 0; k < K_; ++k) {
        float dx = px - cx[k], dy = py - cy[k], dz = pz - cz[k];
        float d2 = dx*dx + dy*dy + dz*dz;
        bool in = (d2 < R2);
        mv[k] = in ? 1.0f : 0.0f;
        if (in) m |= (1u << k);
        if (d2 < best) { best = d2; bi = k; }
    }
    if (valid) {
        #pragma unroll
        for (int k = 0; k < K_; ++k) maskf[(size_t)k*P_ + p] = mv[k];
        nearest[p] = (unsigned char)bi;
    }
    // per-wave popcount per cavity -> LDS -> one global atomic per cavity per block
    int lane = tid & 63;
    #pragma unroll
    for (int k = 0; k < K_; ++k) {
        unsigned long long bal = __ballot(valid && ((m >> k) & 1u));
        if (lane == 0) atomicAdd(&sm[k], (int)__popcll(bal));
    }
    __syncthreads();
    if (tid < K_) atomicAdd(&counts[tid], sm[tid]);
}

// -------------------- kernel 2: masked pooling sums (FMA with float masks) --------------------
// grid = 256 blocks; 512 threads; each block owns 4 consecutive (b,c) rows.
__global__ __launch_bounds__(512) void pool_kernel(const float* __restrict__ x,
                                                   const float* __restrict__ maskf,
                                                   float* __restrict__ sums) {
    int r0 = blockIdx.x * 4;
    int tid = threadIdx.x;
    const float4* xr0 = (const float4*)(x + (size_t)(r0+0) * P_);
    const float4* xr1 = (const float4*)(x + (size_t)(r0+1) * P_);
    const float4* xr2 = (const float4*)(x + (size_t)(r0+2) * P_);
    const float4* xr3 = (const float4*)(x + (size_t)(r0+3) * P_);
    const float4* mf4 = (const float4*)maskf;   // plane k starts at k*(P_/4) float4s
    float acc[4][K_];
    #pragma unroll
    for (int r = 0; r < 4; ++r)
        #pragma unroll
        for (int k = 0; k < K_; ++k) acc[r][k] = 0.f;
    for (int i = tid; i < P_/4; i += 512) {
        float4 xv0 = xr0[i], xv1 = xr1[i], xv2 = xr2[i], xv3 = xr3[i];
        #pragma unroll
        for (int k = 0; k < K_; ++k) {
            float4 mf = mf4[(size_t)k*(P_/4) + i];
            acc[0][k] = fmaf(xv0.x, mf.x, fmaf(xv0.y, mf.y, fmaf(xv0.z, mf.z, fmaf(xv0.w, mf.w, acc[0][k]))));
            acc[1][k] = fmaf(xv1.x, mf.x, fmaf(xv1.y, mf.y, fmaf(xv1.z, mf.z, fmaf(xv1.w, mf.w, acc[1][k]))));
            acc[2][k] = fmaf(xv2.x, mf.x, fmaf(xv2.y, mf.y, fmaf(xv2.z, mf.z, fmaf(xv2.w, mf.w, acc[2][k]))));
            acc[3][k] = fmaf(xv3.x, mf.x, fmaf(xv3.y, mf.y, fmaf(xv3.z, mf.z, fmaf(xv3.w, mf.w, acc[3][k]))));
        }
    }
    // wave butterfly reduce, then cross-wave via LDS
    int lane = tid & 63, wave = tid >> 6;
    __shared__ float lsum[8][4][K_];
    #pragma unroll
    for (int r = 0; r < 4; ++r) {
        #pragma unroll
        for (int k = 0; k < K_; ++k) {
            float v = acc[r][k];
            #pragma unroll
            for (int off = 32; off > 0; off >>= 1) v += __shfl_down(v, off);
            if (lane == 0) lsum[wave][r][k] = v;
        }
    }
    __syncthreads();
    if (tid < 4*K_) {
        int r = tid / K_, k = tid % K_;
        float t = 0.f;
        #pragma unroll
        for (int w = 0; w < 8; ++w) t += lsum[w][r][k];
        int row = r0 + r;
        int b = row >> 7, c = row & (C_-1);
        sums[((size_t)b*K_ + k)*C_ + c] = t;
    }
}

// -------------------- kernel 3: feat + per-cavity MLP + qkv projection --------------------
// grid = B*K blocks, 256 threads
__global__ void mlp_kernel(const float* __restrict__ sums,
                           const int* __restrict__ counts,
                           const float* __restrict__ w1,
                           const float* __restrict__ b1,
                           const float* __restrict__ w2,
                           const float* __restrict__ b2,
                           const float* __restrict__ in_w,
                           const float* __restrict__ in_b,
                           float* __restrict__ qkv_out) {
    int b = blockIdx.x / K_, k = blockIdx.x % K_;
    int tid = threadIdx.x;
    __shared__ float feat[C_];
    __shared__ float h[C2_];
    __shared__ float pr[C_];
    int cnt = counts[k];
    float inv = (cnt > 0) ? (1.f / (float)cnt) : 0.f;
    if (tid < C_) feat[tid] = sums[((size_t)b*K_ + k)*C_ + tid] * inv;
    __syncthreads();
    // layer1: h[d] = relu(b1 + feat . w1[k,d,:])   d in [0,256)
    {
        const float* w1r = w1 + ((size_t)k*C2_ + tid)*C_;
        float a = b1[k*C2_ + tid];
        #pragma unroll 8
        for (int c = 0; c < C_; ++c) a += feat[c] * w1r[c];
        h[tid] = fmaxf(a, 0.f);
    }
    __syncthreads();
    // layer2: pr[c] = tanh(b2 + h . w2[k,c,:])  c in [0,128)
    if (tid < C_) {
        const float* w2r = w2 + ((size_t)k*C_ + tid)*C2_;
        float a = b2[k*C_ + tid];
        #pragma unroll 8
        for (int d = 0; d < C2_; ++d) a += h[d] * w2r[d];
        pr[tid] = tanhf(a);
    }
    __syncthreads();
    // qkv: qkv_out[b,k,e] = in_b[e] + pr . in_w[e,:]
    for (int e = tid; e < E3_; e += 256) {
        const float* wr = in_w + (size_t)e*C_;
        float a = in_b[e];
        #pragma unroll 8
        for (int c = 0; c < C_; ++c) a += pr[c] * wr[c];
        qkv_out[((size_t)b*K_ + k)*E3_ + e] = a;
    }
}

// -------------------- kernel 4: MHA over K cavities + out proj --------------------
// grid = B blocks, 256 threads
__global__ void attn_kernel(const float* __restrict__ qkv_in,
                            const float* __restrict__ out_w,
                            const float* __restrict__ out_b,
                            float* __restrict__ att) {
    int b = blockIdx.x;
    int tid = threadIdx.x;
    __shared__ float qkv[K_][E3_];
    __shared__ float ov[K_][C_];
    for (int i = tid; i < K_*E3_; i += 256) qkv[i / E3_][i % E3_] = qkv_in[(size_t)b*K_*E3_ + i];
    __syncthreads();
    // attention rows: (h,q) pairs = 8*14 = 112
    if (tid < H_*K_) {
        int hh = tid / K_, q = tid % K_;
        const float* qv = &qkv[q][hh*DH_];
        float sc[K_];
        float mx = -1e30f;
        #pragma unroll
        for (int kk = 0; kk < K_; ++kk) {
            float a = 0.f;
            #pragma unroll
            for (int d = 0; d < DH_; ++d) a += qv[d] * qkv[kk][C_ + hh*DH_ + d];
            a *= 0.25f;   // 1/sqrt(16)
            sc[kk] = a;
            mx = fmaxf(mx, a);
        }
        float ssum = 0.f;
        #pragma unroll
        for (int kk = 0; kk < K_; ++kk) { sc[kk] = __expf(sc[kk] - mx); ssum += sc[kk]; }
        float rinv = 1.f / ssum;
        #pragma unroll
        for (int d = 0; d < DH_; ++d) {
            float a = 0.f;
            #pragma unroll
            for (int kk = 0; kk < K_; ++kk) a += sc[kk] * qkv[kk][2*C_ + hh*DH_ + d];
            ov[q][hh*DH_ + d] = a * rinv;
        }
    }
    __syncthreads();
    // out proj: att[b,k,o] = out_b[o] + sum_c ov[k][c]*out_w[o,c]
    for (int i = tid; i < K_*C_; i += 256) {
        int kk = i / C_, o = i % C_;
        const float* wr = out_w + (size_t)o*C_;
        float a = out_b[o];
        #pragma unroll 8
        for (int c = 0; c < C_; ++c) a += ov[kk][c] * wr[c];
        att[((size_t)b*K_ + kk)*C_ + o] = a;
    }
}

// -------------------- kernel 5: gather-add back to points --------------------
// grid = (13, B*C), 256 threads, stride loop; non-temporal stores keep out of L3
__global__ void gather_kernel(const float* __restrict__ x,
                              const float* __restrict__ att,
                              const unsigned char* __restrict__ nearest,
                              float* __restrict__ out) {
    int row = blockIdx.y;            // b*C + c
    int b = row >> 7, c = row & (C_-1);
    __shared__ float al[K_];
    if (threadIdx.x < K_) al[threadIdx.x] = att[((size_t)b*K_ + threadIdx.x)*C_ + c];
    __syncthreads();
    const float4* xr = (const float4*)(x + (size_t)row * P_);
    f32x4_t* orow = (f32x4_t*)(out + (size_t)row * P_);
    const uchar4* nr = (const uchar4*)nearest;
    for (int i = blockIdx.x * blockDim.x + threadIdx.x; i < P_/4; i += 13*256) {
        float4 xv = xr[i];
        uchar4 nv = nr[i];
        f32x4_t o;
        o.x = xv.x + al[nv.x];
        o.y = xv.y + al[nv.y];
        o.z = xv.z + al[nv.z];
        o.w = xv.w + al[nv.w];
        __builtin_nontemporal_store(o, &orow[i]);
    }
}

extern "C" void kernel_launch(void* const* d_in, const int* in_sizes, int n_in,
                              void* d_out, int out_size, void* d_ws, size_t ws_size,
                              hipStream_t stream) {
    const float* x      = (const float*)d_in[0];
    const float* points = (const float*)d_in[1];
    const float* cav    = (const float*)d_in[2];
    const float* w1     = (const float*)d_in[3];
    const float* b1     = (const float*)d_in[4];
    const float* w2     = (const float*)d_in[5];
    const float* b2     = (const float*)d_in[6];
    const float* in_w   = (const float*)d_in[7];
    const float* in_b   = (const float*)d_in[8];
    const float* out_w  = (const float*)d_in[9];
    const float* out_b  = (const float*)d_in[10];
    float* out = (float*)d_out;

    // workspace carve (all offsets 256B-aligned)
    char* w = (char*)d_ws;
    float*          maskf   = (float*)(w + 0);                 // 14*100000*4 = 5,600,000 B
    unsigned char*  nearest = (unsigned char*)(w + 5600000);   // 100,000 B
    int*            counts  = (int*)(w + 5700096);             // 56 B
    float*          sums    = (float*)(w + 5700352);           // 57,344 B
    float*          qkv     = (float*)(w + 5757696);           // 172,032 B
    float*          att     = (float*)(w + 5929728);           // 57,344 B

    (void)hipMemsetAsync(counts, 0, K_ * sizeof(int), stream);
    geom_kernel<<<(P_ + 255)/256, 256, 0, stream>>>(points, cav, maskf, nearest, counts);
    pool_kernel<<<256, 512, 0, stream>>>(x, maskf, sums);
    mlp_kernel<<<B_*K_, 256, 0, stream>>>(sums, counts, w1, b1, w2, b2, in_w, in_b, qkv);
    attn_kernel<<<B_, 256, 0, stream>>>(qkv, out_w, out_b, att);
    gather_kernel<<<dim3(13, B_*C_), 256, 0, stream>>>(x, att, nearest, out);
}

// Round 5
// 299.406 us; speedup vs baseline: 1.2573x; 1.2573x over previous
//
#include <hip/hip_runtime.h>
#include <hip/hip_bf16.h>
#include <math.h>

#define B_ 8
#define C_ 128
#define P_ 100000
#define K_ 14
#define H_ 8
#define DH_ 16
#define C2_ (2*C_)
#define E3_ (3*C_)
#define R2 0.25f

typedef float f32x4_t __attribute__((ext_vector_type(4)));

__device__ __forceinline__ int bitsel(unsigned m, int k) {
#if __has_builtin(__builtin_amdgcn_sbfe)
    return __builtin_amdgcn_sbfe((int)m, (unsigned)k, 1u);
#else
    return ((int)(m << (31 - k))) >> 31;
#endif
}

// -------------------- kernel 1: geometry -> u16 mask + nearest + counts --------------------
__global__ void geom_kernel(const float* __restrict__ pts,
                            const float* __restrict__ cav,
                            unsigned short* __restrict__ mask,
                            unsigned char* __restrict__ nearest,
                            int* __restrict__ counts) {
    __shared__ float cx[K_], cy[K_], cz[K_];
    __shared__ int sm[K_];
    int tid = threadIdx.x;
    if (tid < K_) {
        cx[tid] = cav[tid*3+0];
        cy[tid] = cav[tid*3+1];
        cz[tid] = cav[tid*3+2];
        sm[tid] = 0;
    }
    __syncthreads();
    int p = blockIdx.x * blockDim.x + tid;
    bool valid = (p < P_);
    int pc = valid ? p : (P_ - 1);
    float px = pts[pc*3+0], py = pts[pc*3+1], pz = pts[pc*3+2];
    unsigned m = 0;
    float best = 1e30f;
    int bi = 0;
    #pragma unroll
    for (int k = 0; k < K_; ++k) {
        float dx = px - cx[k], dy = py - cy[k], dz = pz - cz[k];
        float d2 = dx*dx + dy*dy + dz*dz;
        if (d2 < R2) m |= (1u << k);
        if (d2 < best) { best = d2; bi = k; }
    }
    if (valid) {
        mask[p] = (unsigned short)m;
        nearest[p] = (unsigned char)bi;
    }
    int lane = tid & 63;
    #pragma unroll
    for (int k = 0; k < K_; ++k) {
        unsigned long long bal = __ballot(valid && ((m >> k) & 1u));
        if (lane == 0) atomicAdd(&sm[k], (int)__popcll(bal));
    }
    __syncthreads();
    if (tid < K_) atomicAdd(&counts[tid], sm[tid]);
}

// -------------------- kernel 2: masked pooling, u16 masks, decode shared over 4 rows --------------------
// grid = 256 blocks; 512 threads; each block owns 4 consecutive (b,c) rows.
__global__ __launch_bounds__(512) void pool_kernel(const float* __restrict__ x,
                                                   const unsigned short* __restrict__ mask,
                                                   float* __restrict__ sums) {
    int r0 = blockIdx.x * 4;
    int tid = threadIdx.x;
    const float4* xr0 = (const float4*)(x + (size_t)(r0+0) * P_);
    const float4* xr1 = (const float4*)(x + (size_t)(r0+1) * P_);
    const float4* xr2 = (const float4*)(x + (size_t)(r0+2) * P_);
    const float4* xr3 = (const float4*)(x + (size_t)(r0+3) * P_);
    const ushort4* mr = (const ushort4*)mask;
    float acc[4][K_];
    #pragma unroll
    for (int r = 0; r < 4; ++r)
        #pragma unroll
        for (int k = 0; k < K_; ++k) acc[r][k] = 0.f;
    for (int i = tid; i < P_/4; i += 512) {
        ushort4 mv = mr[i];
        unsigned ma = mv.x, mb = mv.y, mc = mv.z, md = mv.w;
        float4 xv0 = xr0[i], xv1 = xr1[i], xv2 = xr2[i], xv3 = xr3[i];
        #pragma unroll
        for (int k = 0; k < K_; ++k) {
            // decode bit k of 4 mask elems to 0.0f/1.0f once, reuse for 4 rows
            float m0 = __int_as_float(bitsel(ma, k) & 0x3f800000);
            float m1 = __int_as_float(bitsel(mb, k) & 0x3f800000);
            float m2 = __int_as_float(bitsel(mc, k) & 0x3f800000);
            float m3 = __int_as_float(bitsel(md, k) & 0x3f800000);
            acc[0][k] = fmaf(xv0.x, m0, fmaf(xv0.y, m1, fmaf(xv0.z, m2, fmaf(xv0.w, m3, acc[0][k]))));
            acc[1][k] = fmaf(xv1.x, m0, fmaf(xv1.y, m1, fmaf(xv1.z, m2, fmaf(xv1.w, m3, acc[1][k]))));
            acc[2][k] = fmaf(xv2.x, m0, fmaf(xv2.y, m1, fmaf(xv2.z, m2, fmaf(xv2.w, m3, acc[2][k]))));
            acc[3][k] = fmaf(xv3.x, m0, fmaf(xv3.y, m1, fmaf(xv3.z, m2, fmaf(xv3.w, m3, acc[3][k]))));
        }
    }
    // wave butterfly reduce, then cross-wave via LDS
    int lane = tid & 63, wave = tid >> 6;
    __shared__ float lsum[8][4][K_];
    #pragma unroll
    for (int r = 0; r < 4; ++r) {
        #pragma unroll
        for (int k = 0; k < K_; ++k) {
            float v = acc[r][k];
            #pragma unroll
            for (int off = 32; off > 0; off >>= 1) v += __shfl_down(v, off);
            if (lane == 0) lsum[wave][r][k] = v;
        }
    }
    __syncthreads();
    if (tid < 4*K_) {
        int r = tid / K_, k = tid % K_;
        float t = 0.f;
        #pragma unroll
        for (int w = 0; w < 8; ++w) t += lsum[w][r][k];
        int row = r0 + r;
        int b = row >> 7, c = row & (C_-1);
        sums[((size_t)b*K_ + k)*C_ + c] = t;
    }
}

// -------------------- kernel 3: feat + per-cavity MLP + qkv projection --------------------
// grid = B*K blocks, 256 threads
__global__ void mlp_kernel(const float* __restrict__ sums,
                           const int* __restrict__ counts,
                           const float* __restrict__ w1,
                           const float* __restrict__ b1,
                           const float* __restrict__ w2,
                           const float* __restrict__ b2,
                           const float* __restrict__ in_w,
                           const float* __restrict__ in_b,
                           float* __restrict__ qkv_out) {
    int b = blockIdx.x / K_, k = blockIdx.x % K_;
    int tid = threadIdx.x;
    __shared__ float feat[C_];
    __shared__ float h[C2_];
    __shared__ float pr[C_];
    int cnt = counts[k];
    float inv = (cnt > 0) ? (1.f / (float)cnt) : 0.f;
    if (tid < C_) feat[tid] = sums[((size_t)b*K_ + k)*C_ + tid] * inv;
    __syncthreads();
    {
        const float* w1r = w1 + ((size_t)k*C2_ + tid)*C_;
        float a = b1[k*C2_ + tid];
        #pragma unroll 8
        for (int c = 0; c < C_; ++c) a += feat[c] * w1r[c];
        h[tid] = fmaxf(a, 0.f);
    }
    __syncthreads();
    if (tid < C_) {
        const float* w2r = w2 + ((size_t)k*C_ + tid)*C2_;
        float a = b2[k*C_ + tid];
        #pragma unroll 8
        for (int d = 0; d < C2_; ++d) a += h[d] * w2r[d];
        pr[tid] = tanhf(a);
    }
    __syncthreads();
    for (int e = tid; e < E3_; e += 256) {
        const float* wr = in_w + (size_t)e*C_;
        float a = in_b[e];
        #pragma unroll 8
        for (int c = 0; c < C_; ++c) a += pr[c] * wr[c];
        qkv_out[((size_t)b*K_ + k)*E3_ + e] = a;
    }
}

// -------------------- kernel 4: MHA over K cavities + out proj --------------------
// grid = B blocks, 256 threads
__global__ void attn_kernel(const float* __restrict__ qkv_in,
                            const float* __restrict__ out_w,
                            const float* __restrict__ out_b,
                            float* __restrict__ att) {
    int b = blockIdx.x;
    int tid = threadIdx.x;
    __shared__ float qkv[K_][E3_];
    __shared__ float ov[K_][C_];
    for (int i = tid; i < K_*E3_; i += 256) qkv[i / E3_][i % E3_] = qkv_in[(size_t)b*K_*E3_ + i];
    __syncthreads();
    if (tid < H_*K_) {
        int hh = tid / K_, q = tid % K_;
        const float* qv = &qkv[q][hh*DH_];
        float sc[K_];
        float mx = -1e30f;
        #pragma unroll
        for (int kk = 0; kk < K_; ++kk) {
            float a = 0.f;
            #pragma unroll
            for (int d = 0; d < DH_; ++d) a += qv[d] * qkv[kk][C_ + hh*DH_ + d];
            a *= 0.25f;
            sc[kk] = a;
            mx = fmaxf(mx, a);
        }
        float ssum = 0.f;
        #pragma unroll
        for (int kk = 0; kk < K_; ++kk) { sc[kk] = __expf(sc[kk] - mx); ssum += sc[kk]; }
        float rinv = 1.f / ssum;
        #pragma unroll
        for (int d = 0; d < DH_; ++d) {
            float a = 0.f;
            #pragma unroll
            for (int kk = 0; kk < K_; ++kk) a += sc[kk] * qkv[kk][2*C_ + hh*DH_ + d];
            ov[q][hh*DH_ + d] = a * rinv;
        }
    }
    __syncthreads();
    for (int i = tid; i < K_*C_; i += 256) {
        int kk = i / C_, o = i % C_;
        const float* wr = out_w + (size_t)o*C_;
        float a = out_b[o];
        #pragma unroll 8
        for (int c = 0; c < C_; ++c) a += ov[kk][c] * wr[c];
        att[((size_t)b*K_ + kk)*C_ + o] = a;
    }
}

// -------------------- kernel 5: gather-add, reverse-streamed for L3 reuse --------------------
// grid = (13, B*C), 256 threads; iterate P from the tail (hot in L3 after pool)
__global__ void gather_kernel(const float* __restrict__ x,
                              const float* __restrict__ att,
                              const unsigned char* __restrict__ nearest,
                              float* __restrict__ out) {
    int row = blockIdx.y;            // b*C + c
    int b = row >> 7, c = row & (C_-1);
    __shared__ float al[K_];
    if (threadIdx.x < K_) al[threadIdx.x] = att[((size_t)b*K_ + threadIdx.x)*C_ + c];
    __syncthreads();
    const float4* xr = (const float4*)(x + (size_t)row * P_);
    f32x4_t* orow = (f32x4_t*)(out + (size_t)row * P_);
    const uchar4* nr = (const uchar4*)nearest;
    for (int j = blockIdx.x * blockDim.x + threadIdx.x; j < P_/4; j += 13*256) {
        int i = P_/4 - 1 - j;        // tail-first: those lines are L3-resident from pool
        float4 xv = xr[i];
        uchar4 nv = nr[i];
        f32x4_t o;
        o.x = xv.x + al[nv.x];
        o.y = xv.y + al[nv.y];
        o.z = xv.z + al[nv.z];
        o.w = xv.w + al[nv.w];
        __builtin_nontemporal_store(o, &orow[i]);
    }
}

extern "C" void kernel_launch(void* const* d_in, const int* in_sizes, int n_in,
                              void* d_out, int out_size, void* d_ws, size_t ws_size,
                              hipStream_t stream) {
    const float* x      = (const float*)d_in[0];
    const float* points = (const float*)d_in[1];
    const float* cav    = (const float*)d_in[2];
    const float* w1     = (const float*)d_in[3];
    const float* b1     = (const float*)d_in[4];
    const float* w2     = (const float*)d_in[5];
    const float* b2     = (const float*)d_in[6];
    const float* in_w   = (const float*)d_in[7];
    const float* in_b   = (const float*)d_in[8];
    const float* out_w  = (const float*)d_in[9];
    const float* out_b  = (const float*)d_in[10];
    float* out = (float*)d_out;

    // workspace carve (all offsets 256B-aligned)
    char* w = (char*)d_ws;
    unsigned short* mask    = (unsigned short*)(w + 0);        // 200,000 B
    unsigned char*  nearest = (unsigned char*)(w + 200192);    // 100,000 B
    int*            counts  = (int*)(w + 300288);              // 56 B
    float*          sums    = (float*)(w + 300544);            // 57,344 B
    float*          qkv     = (float*)(w + 358144);            // 172,032 B
    float*          att     = (float*)(w + 530432);            // 57,344 B

    (void)hipMemsetAsync(counts, 0, K_ * sizeof(int), stream);
    geom_kernel<<<(P_ + 255)/256, 256, 0, stream>>>(points, cav, mask, nearest, counts);
    pool_kernel<<<256, 512, 0, stream>>>(x, mask, sums);
    mlp_kernel<<<B_*K_, 256, 0, stream>>>(sums, counts, w1, b1, w2, b2, in_w, in_b, qkv);
    attn_kernel<<<B_, 256, 0, stream>>>(qkv, out_w, out_b, att);
    gather_kernel<<<dim3(13, B_*C_), 256, 0, stream>>>(x, att, nearest, out);
}